// Round 3
// baseline (682.964 us; speedup 1.0000x reference)
//
#include <hip/hip_runtime.h>
#include <math.h>

#define TPB 256
#define RC 64          // row chunks per sequence

// ---------------------------------------------------------------------------
// Kernel 1 (fast path, D==4096): masked per-segment partial column sums.
// grid: (RC, B). Each block owns a CONTIGUOUS row range [r_lo, r_hi) of its
// sequence and reads ALL columns -> purely linear memory sweep (memcpy-like).
// Thread t accumulates 4 column positions: q*1024 + t*4, q in 0..3.
// Rows unrolled x2 with separate accumulator sets -> 8 loads in flight.
// ---------------------------------------------------------------------------
__global__ void __launch_bounds__(TPB) grit_partial4096(
    const float* __restrict__ hs,
    const int* __restrict__ plens,
    const int* __restrict__ ilens,
    float* __restrict__ partials)
{
    const int D = 4096;
    const int b  = blockIdx.y;
    const int ry = blockIdx.x;
    const int plen = plens[b];
    const int ilen = ilens[b];

    int start = 0;                       // segment start (wave-uniform)
    for (int i = 0; i < b; ++i) start += plens[i];

    const int rpc = (plen + RC - 1) / RC;
    int r_lo = ry * rpc;
    int r_hi = r_lo + rpc;
    if (r_hi > plen) r_hi = plen;
    if (r_lo < ilen) r_lo = ilen;        // mask instruction tokens

    const int t = threadIdx.x;
    float4 A0 = make_float4(0.f,0.f,0.f,0.f), A1 = A0, A2 = A0, A3 = A0;
    float4 B0 = A0, B1 = A0, B2 = A0, B3 = A0;

    if (r_lo < r_hi) {
        const float* rp = hs + (size_t)(start + r_lo) * (size_t)D + t * 4;
        int r = r_lo;
        for (; r + 2 <= r_hi; r += 2) {
            const float4 v0 = *(const float4*)(rp);
            const float4 v1 = *(const float4*)(rp + 1024);
            const float4 v2 = *(const float4*)(rp + 2048);
            const float4 v3 = *(const float4*)(rp + 3072);
            const float4 w0 = *(const float4*)(rp + 4096);
            const float4 w1 = *(const float4*)(rp + 4096 + 1024);
            const float4 w2 = *(const float4*)(rp + 4096 + 2048);
            const float4 w3 = *(const float4*)(rp + 4096 + 3072);
            rp += 8192;
            A0.x += v0.x; A0.y += v0.y; A0.z += v0.z; A0.w += v0.w;
            A1.x += v1.x; A1.y += v1.y; A1.z += v1.z; A1.w += v1.w;
            A2.x += v2.x; A2.y += v2.y; A2.z += v2.z; A2.w += v2.w;
            A3.x += v3.x; A3.y += v3.y; A3.z += v3.z; A3.w += v3.w;
            B0.x += w0.x; B0.y += w0.y; B0.z += w0.z; B0.w += w0.w;
            B1.x += w1.x; B1.y += w1.y; B1.z += w1.z; B1.w += w1.w;
            B2.x += w2.x; B2.y += w2.y; B2.z += w2.z; B2.w += w2.w;
            B3.x += w3.x; B3.y += w3.y; B3.z += w3.z; B3.w += w3.w;
        }
        if (r < r_hi) {
            const float4 v0 = *(const float4*)(rp);
            const float4 v1 = *(const float4*)(rp + 1024);
            const float4 v2 = *(const float4*)(rp + 2048);
            const float4 v3 = *(const float4*)(rp + 3072);
            A0.x += v0.x; A0.y += v0.y; A0.z += v0.z; A0.w += v0.w;
            A1.x += v1.x; A1.y += v1.y; A1.z += v1.z; A1.w += v1.w;
            A2.x += v2.x; A2.y += v2.y; A2.z += v2.z; A2.w += v2.w;
            A3.x += v3.x; A3.y += v3.y; A3.z += v3.z; A3.w += v3.w;
        }
    }
    A0.x += B0.x; A0.y += B0.y; A0.z += B0.z; A0.w += B0.w;
    A1.x += B1.x; A1.y += B1.y; A1.z += B1.z; A1.w += B1.w;
    A2.x += B2.x; A2.y += B2.y; A2.z += B2.z; A2.w += B2.w;
    A3.x += B3.x; A3.y += B3.y; A3.z += B3.z; A3.w += B3.w;

    // always store (zeros too — ws is poisoned 0xAA before every launch)
    float* dst = partials + (size_t)(b * RC + ry) * (size_t)D + t * 4;
    *(float4*)(dst)        = A0;
    *(float4*)(dst + 1024) = A1;
    *(float4*)(dst + 2048) = A2;
    *(float4*)(dst + 3072) = A3;
}

// Generic fallback (any D multiple of 4): strided column-strip version.
__global__ void __launch_bounds__(TPB) grit_partial_generic(
    const float* __restrict__ hs,
    const int* __restrict__ plens,
    const int* __restrict__ ilens,
    float* __restrict__ partials,
    int D)
{
    const int b  = blockIdx.z;
    const int ry = blockIdx.y;
    const int plen = plens[b];
    const int ilen = ilens[b];
    int start = 0;
    for (int i = 0; i < b; ++i) start += plens[i];
    const int rpc = (plen + RC - 1) / RC;
    int r_lo = ry * rpc;
    int r_hi = r_lo + rpc;
    if (r_hi > plen) r_hi = plen;
    if (r_lo < ilen) r_lo = ilen;
    const int col = (blockIdx.x * TPB + threadIdx.x) * 4;
    if (col >= D) return;
    float4 a = make_float4(0.f,0.f,0.f,0.f);
    for (int r = r_lo; r < r_hi; ++r) {
        const float4 v = *(const float4*)(hs + (size_t)(start + r) * (size_t)D + col);
        a.x += v.x; a.y += v.y; a.z += v.z; a.w += v.w;
    }
    *(float4*)(partials + (size_t)(b * RC + ry) * (size_t)D + col) = a;
}

// ---------------------------------------------------------------------------
// Kernel 2: chunk-reduce + mean. grid: (ceil(D/1024), B). Writes mean to out,
// per-block sum-of-squared-means to sqws[b*CX + cx].
// ---------------------------------------------------------------------------
__global__ void __launch_bounds__(TPB) grit_reduce_kernel(
    const int* __restrict__ plens,
    const int* __restrict__ ilens,
    const float* __restrict__ partials,
    float* __restrict__ out,
    float* __restrict__ sqws,
    int D, int CX)
{
    const int b  = blockIdx.y;
    const int cx = blockIdx.x;
    const int c  = cx * (TPB * 4) + threadIdx.x * 4;
    const float inv = 1.0f / (float)(plens[b] - ilens[b]);

    float sq = 0.f;
    if (c < D) {
        const float* p = partials + (size_t)b * RC * (size_t)D + c;
        float4 s = make_float4(0.f,0.f,0.f,0.f);
        #pragma unroll 8
        for (int ry = 0; ry < RC; ++ry) {
            const float4 v = *(const float4*)(p + (size_t)ry * (size_t)D);
            s.x += v.x; s.y += v.y; s.z += v.z; s.w += v.w;
        }
        float4 m;
        m.x = s.x * inv; m.y = s.y * inv; m.z = s.z * inv; m.w = s.w * inv;
        sq = m.x*m.x + m.y*m.y + m.z*m.z + m.w*m.w;
        *(float4*)(out + (size_t)b * (size_t)D + c) = m;
    }

    #pragma unroll
    for (int off = 32; off > 0; off >>= 1)
        sq += __shfl_down(sq, off, 64);

    __shared__ float wsum[TPB / 64];
    const int lane = threadIdx.x & 63;
    const int wave = threadIdx.x >> 6;
    if (lane == 0) wsum[wave] = sq;
    __syncthreads();

    if (threadIdx.x == 0) {
        float total = 0.f;
        #pragma unroll
        for (int w = 0; w < TPB / 64; ++w) total += wsum[w];
        sqws[b * CX + cx] = total;
    }
}

// ---------------------------------------------------------------------------
// Kernel 3: normalize. grid: B blocks. out is L2-hot (256 KiB total).
// ---------------------------------------------------------------------------
__global__ void __launch_bounds__(TPB) grit_norm_kernel(
    const float* __restrict__ sqws,
    float* __restrict__ out,
    int D, int CX)
{
    const int b = blockIdx.x;
    float total = 0.f;
    for (int i = 0; i < CX; ++i) total += sqws[b * CX + i];
    const float invn = 1.0f / fmaxf(sqrtf(total), 1e-12f);

    float* o = out + (size_t)b * (size_t)D;
    for (int col = threadIdx.x * 4; col < D; col += TPB * 4) {
        float4 m = *(const float4*)(o + col);
        m.x *= invn; m.y *= invn; m.z *= invn; m.w *= invn;
        *(float4*)(o + col) = m;
    }
}

extern "C" void kernel_launch(void* const* d_in, const int* in_sizes, int n_in,
                              void* d_out, int out_size, void* d_ws, size_t ws_size,
                              hipStream_t stream) {
    const float* hs    = (const float*)d_in[0];
    const int*   plens = (const int*)d_in[1];
    const int*   ilens = (const int*)d_in[2];
    float*       out   = (float*)d_out;

    const int B = in_sizes[1];          // 16
    const int D = out_size / B;         // 4096

    float* partials = (float*)d_ws;                              // [B*RC, D]
    float* sqws     = partials + (size_t)B * RC * (size_t)D;     // [B, CX]
    const int CX = (D + TPB * 4 - 1) / (TPB * 4);                // 4

    if (D == 4096) {
        dim3 grid(RC, B);                                        // 1024 blocks
        grit_partial4096<<<grid, TPB, 0, stream>>>(hs, plens, ilens, partials);
    } else {
        dim3 grid(CX, RC, B);
        grit_partial_generic<<<grid, TPB, 0, stream>>>(hs, plens, ilens, partials, D);
    }

    dim3 rgrid(CX, B);                                           // 64 blocks
    grit_reduce_kernel<<<rgrid, TPB, 0, stream>>>(plens, ilens, partials, out, sqws, D, CX);

    grit_norm_kernel<<<B, TPB, 0, stream>>>(sqws, out, D, CX);
}